// Round 3
// baseline (250.566 us; speedup 1.0000x reference)
//
#include <hip/hip_runtime.h>
#include <cmath>

// Round 10: QKV GEMM K-loop fragment loads converted to inline-asm
// ds_read_b128 with immediate offsets. Theory: compiler-visible C++ LDS reads
// force SIInsertWaitcnts to guard against in-flight global_load_lds DMA
// (possible alias) with conservative per-phase vmcnt waits -> ~590cy/phase
// stall (5670 cy/tile vs m201's 3300). asm ds_read is opaque to the waitcnt
// pass; our own lgkmcnt(0) + sched_barrier(0) (rule #18) carries correctness.
// Swizzle term is fragment-invariant -> 4 base addr VGPRs + offset: imms,
// killing per-phase addr VALU too. Sync structure identical to round 9.
// B=4 T=2048 C=1024 H=16 hd=64.

typedef short short8 __attribute__((ext_vector_type(8)));
typedef short short4v __attribute__((ext_vector_type(4)));
typedef float f32x4 __attribute__((ext_vector_type(4)));

__device__ __forceinline__ short f2bf(float f) {
  unsigned u = __builtin_bit_cast(unsigned, f);
  u = (u + 0x7fffu + ((u >> 16) & 1u)) >> 16;   // RNE; inputs are finite
  return (short)u;
}

__device__ __forceinline__ float exp2_fast(float x) {
  float r;
  asm("v_exp_f32 %0, %1" : "=v"(r) : "v"(x));
  return r;
}

__device__ __forceinline__ void gld_lds16(const void* g, void* l) {
  __builtin_amdgcn_global_load_lds(
      (__attribute__((address_space(1))) void*)g,
      (__attribute__((address_space(3))) void*)l,
      16, 0, 0);
}

// raw barrier, opaque to SIInsertWaitcnts (no implicit counter drain)
__device__ __forceinline__ void barx() {
  asm volatile("s_barrier" ::: "memory");
}

// asm ds_read_b128 at byte address + compile-time offset (waitcnt-opaque)
template <int IMM>
__device__ __forceinline__ short8 dsr(int addr) {
  short8 d;
  asm volatile("ds_read_b128 %0, %1 offset:%2"
               : "=v"(d) : "v"(addr), "n"(IMM));
  return d;
}

// wait own-wave ds_reads; sched_barrier stops MFMA hoisting past it (rule #18)
#define WAITL()                                       \
  asm volatile("s_waitcnt lgkmcnt(0)" ::: "memory");  \
  __builtin_amdgcn_sched_barrier(0);

// ---------------- cast fp32 -> bf16 bits (4 elems/thread) ----------------
__global__ void cast_bf16_kernel(const float* __restrict__ in,
                                 short* __restrict__ out, int n4) {
  int i = blockIdx.x * blockDim.x + threadIdx.x;
  if (i < n4) {
    const float4 v = ((const float4*)in)[i];
    short4v o;
    o.x = f2bf(v.x); o.y = f2bf(v.y); o.z = f2bf(v.z); o.w = f2bf(v.w);
    ((short4v*)out)[i] = o;
  }
}

// ------------- transpose+cast: fp32 [R][C] -> bf16 [C][R] ----------------
__global__ void transpose_cast_kernel(const float* __restrict__ in,
                                      short* __restrict__ out, int R, int C) {
  __shared__ float tile[32][33];
  int c0 = blockIdx.x * 32, r0 = blockIdx.y * 32;
  int tx = threadIdx.x & 31, tg = threadIdx.x >> 5;
#pragma unroll
  for (int i = 0; i < 4; ++i) {
    int r = tg * 4 + i;
    tile[r][tx] = in[(size_t)(r0 + r) * C + c0 + tx];
  }
  __syncthreads();
#pragma unroll
  for (int i = 0; i < 4; ++i) {
    int c = tg * 4 + i;
    out[(size_t)(c0 + c) * R + r0 + tx] = f2bf(tile[tx][c]);
  }
}

// --------------- QKV GEMM: 256x256 tile, 8-wave phase pipeline -----------
// C = A[M][K] * Bt[N][K]^T + bias; outputs split to q/k (bf16 [bh][t][d],
// q scaled by log2e/8) and vT (bf16 [bh][d][t]). M=8192 N=3072 K=1024.
// 512 threads = 8 waves (2M x 4N), per-wave C = 128x64 (8x4 16x16 frags).
// LDS: dbuf x (A 256x64 + B 256x64) bf16 = 128KB (dynamic). XOR-swizzled
// via pre-swizzled global source (linear LDS dest, gld_lds requirement).

#define DOMFMA(mp)                                                           \
  __builtin_amdgcn_s_setprio(1);                                             \
  _Pragma("unroll") for (int i_ = 0; i_ < 2; ++i_)                           \
  _Pragma("unroll") for (int n_ = 0; n_ < 4; ++n_)                           \
  _Pragma("unroll") for (int kh_ = 0; kh_ < 2; ++kh_)                        \
      acc[(mp) + i_][n_] = __builtin_amdgcn_mfma_f32_16x16x32_bf16(          \
          a[i_][kh_], b[n_][kh_], acc[(mp) + i_][n_], 0, 0, 0);              \
  __builtin_amdgcn_s_setprio(0);

__global__ __launch_bounds__(512, 2) void qkv_gemm_kernel(
    const short* __restrict__ A, const short* __restrict__ Bt,
    const float* __restrict__ bias,
    short* __restrict__ oq, short* __restrict__ ok, short* __restrict__ ovt,
    int M, int N, int K) {
  extern __shared__ short lds[];
  const int NT = K >> 6;  // 16 K-tiles
  const int lane = threadIdx.x & 63, wave = threadIdx.x >> 6;
  const int quad = lane >> 4, l16 = lane & 15;
  const int wm2 = wave >> 2, wn4 = wave & 3;

  // bijective XCD swizzle (grid % 8 == 0); n varies fastest within an XCD.
  const int nbn = N >> 8;
  const int swz = (blockIdx.x & 7) * ((int)gridDim.x >> 3) + (blockIdx.x >> 3);
  const int m0 = (swz / nbn) * 256, n0 = (swz % nbn) * 256;

  // staging: per gld, wave w covers 8 rows (w*8 + lane>>3) x 8 16B segs,
  // global seg XOR-pre-swizzled so linear LDS dest yields swizzled layout.
  const int r8 = lane >> 3;
  const int sw8 = ((lane & 7) ^ r8) * 8;
  const short* Ab0 = A + (size_t)(m0 + wave * 8 + r8) * K + sw8;
  const short* Bb0 = Bt + (size_t)(n0 + wave * 8 + r8) * K + sw8;
  short* ldsw = lds + wave * 512;

  auto stage = [&](int t, int mat, int rA, int rB) {
    const short* g = (mat ? Bb0 : Ab0) + t * 64;
    short* d = ldsw + (t & 1) * 32768 + mat * 16384;
    gld_lds16(g + (size_t)rA * K, d + rA * 64);
    gld_lds16(g + (size_t)rB * K, d + rB * 64);
  };

  // fragment read base addresses (bytes): swizzle term is frag-invariant.
  // frag addr = base + (t&1)*65536 + frag_row16*2048, A row stride 128B.
  const int swz0 = ((0 + quad) ^ (l16 & 7)) * 16;  // kh=0
  const int swz1 = ((4 + quad) ^ (l16 & 7)) * 16;  // kh=1
  const int baseA0 = wm2 * 16384 + l16 * 128 + swz0;
  const int baseA1 = wm2 * 16384 + l16 * 128 + swz1;
  const int baseB0 = 32768 + wn4 * 8192 + l16 * 128 + swz0;
  const int baseB1 = 32768 + wn4 * 8192 + l16 * 128 + swz1;

  f32x4 acc[8][4] = {};

  // prologue: tile0 {B-lo,B-hi,A-lo,A-hi}, tile1 {B-lo,B-hi,A-lo}
  stage(0, 1, 0, 64);
  stage(0, 1, 128, 192);
  stage(0, 0, 0, 128);
  stage(0, 0, 64, 192);
  stage(1, 1, 0, 64);
  stage(1, 1, 128, 192);
  stage(1, 0, 0, 128);
  asm volatile("s_waitcnt vmcnt(6)" ::: "memory");
  barx();

#pragma unroll 1
  for (int t = 0; t < NT; ++t) {
    const int vb = (t & 1) << 16;
    const int aA0 = baseA0 + vb, aA1 = baseA1 + vb;
    const int aB0 = baseB0 + vb, aB1 = baseB1 + vb;
    short8 b[4][2], a[2][2];

    // ---- phase 0: B all (8 reads) + A m0-1; issue (t+1) A-hi chunk ----
    b[0][0] = dsr<0>(aB0);      b[0][1] = dsr<0>(aB1);
    b[1][0] = dsr<2048>(aB0);   b[1][1] = dsr<2048>(aB1);
    b[2][0] = dsr<4096>(aB0);   b[2][1] = dsr<4096>(aB1);
    b[3][0] = dsr<6144>(aB0);   b[3][1] = dsr<6144>(aB1);
    a[0][0] = dsr<0>(aA0);      a[0][1] = dsr<0>(aA1);
    a[1][0] = dsr<2048>(aA0);   a[1][1] = dsr<2048>(aA1);
    if (t + 1 < NT) stage(t + 1, 0, 64, 192);   // cA1(t+1): other buffer
    barx();
    WAITL()
    DOMFMA(0)
    barx();

    // ---- phase 1: A m2-3; issue (t+2) B-lo (B of this buf read-once @P0) --
    a[0][0] = dsr<4096>(aA0);   a[0][1] = dsr<4096>(aA1);
    a[1][0] = dsr<6144>(aA0);   a[1][1] = dsr<6144>(aA1);
    if (t + 2 < NT) stage(t + 2, 1, 0, 64);
    barx();
    WAITL()
    DOMFMA(2)
    barx();

    // ---- phase 2: A m4-5; issue (t+2) B-hi ----
    a[0][0] = dsr<8192>(aA0);   a[0][1] = dsr<8192>(aA1);
    a[1][0] = dsr<10240>(aA0);  a[1][1] = dsr<10240>(aA1);
    if (t + 2 < NT) stage(t + 2, 1, 128, 192);
    barx();
    WAITL()
    DOMFMA(4)
    barx();

    // ---- phase 3: A m6-7; issue (t+2) A-lo (rows last read @P1) ----
    a[0][0] = dsr<12288>(aA0);  a[0][1] = dsr<12288>(aA1);
    a[1][0] = dsr<14336>(aA0);  a[1][1] = dsr<14336>(aA1);
    if (t + 2 < NT) stage(t + 2, 0, 0, 128);
    barx();
    WAITL()
    DOMFMA(6)
    if (t == NT - 2)
      asm volatile("s_waitcnt vmcnt(0)" ::: "memory");  // drain before last tile
    else
      asm volatile("s_waitcnt vmcnt(6)" ::: "memory");  // counted: 3 chunks fly
    barx();
  }

  // ------------------------------ epilogue -------------------------------
  const int sec = n0 >> 10;                 // 0=q 1=k 2=v
  const int h0 = (n0 & 1023) >> 6;
  const float scale = (sec == 0) ? 0.18033688f : 1.0f;  // log2e/8 into q
  float bv[4];
#pragma unroll
  for (int n_ = 0; n_ < 4; ++n_) bv[n_] = bias[n0 + wn4 * 64 + n_ * 16 + l16];
  const int b_ = m0 >> 11, t0 = m0 & 2047;

  if (sec < 2) {
    // two passes over M-halves; Cs[128][264] bf16 (stride 528B: uniform banks)
    short* dst = (sec == 0) ? oq : ok;
#pragma unroll 1
    for (int p = 0; p < 2; ++p) {
      if (wm2 == p) {
#pragma unroll
        for (int mt = 0; mt < 8; ++mt)
#pragma unroll
          for (int n_ = 0; n_ < 4; ++n_) {
            const int col = wn4 * 64 + n_ * 16 + l16;
#pragma unroll
            for (int r = 0; r < 4; ++r)
              lds[(mt * 16 + quad * 4 + r) * 264 + col] =
                  f2bf((acc[mt][n_][r] + bv[n_]) * scale);
          }
      }
      __syncthreads();
      // wave w: head w&3, row-group w>>2; each iter = 8 t-rows x 64 d = 1KB
      const int hl = wave & 3, rg = wave >> 2;
      const short* sp = &lds[(rg * 64 + r8) * 264 + hl * 64 + (lane & 7) * 8];
      short* gp = dst +
          ((size_t)(b_ * 16 + h0 + hl) * 2048 + t0 + p * 128 + rg * 64 + r8) * 64 +
          (lane & 7) * 8;
#pragma unroll
      for (int i = 0; i < 8; ++i)
        *(short8*)(gp + (size_t)i * 512) = *(const short8*)(sp + i * 8 * 264);
      __syncthreads();
    }
  } else {
    // v: transposed repack; Cs[256 cols][136] bf16 per pass
#pragma unroll 1
    for (int p = 0; p < 2; ++p) {
      if (wm2 == p) {
#pragma unroll
        for (int mt = 0; mt < 8; ++mt)
#pragma unroll
          for (int n_ = 0; n_ < 4; ++n_) {
            const int col = wn4 * 64 + n_ * 16 + l16;
#pragma unroll
            for (int r = 0; r < 4; ++r)
              lds[col * 136 + mt * 16 + quad * 4 + r] =
                  f2bf(acc[mt][n_][r] + bv[n_]);
          }
      }
      __syncthreads();
      // wave w covers cols [w*32,+32): iter = 4 d-cols x 128 t = 4x256B
      const int cw = wave * 32 + (lane >> 4);
#pragma unroll
      for (int i = 0; i < 8; ++i) {
        const int c = cw + i * 4;
        const int bh = b_ * 16 + h0 + (c >> 6), d = c & 63;
        *(short8*)(ovt + ((size_t)bh * 64 + d) * 2048 + t0 + p * 128 +
                   (lane & 15) * 8) =
            *(const short8*)&lds[c * 136 + (lane & 15) * 8];
      }
      __syncthreads();
    }
  }
}

// ------------------------- proj GEMM (unchanged) -------------------------
// C[m][n] = sum_k A[m][k]*B[k][n] + bias[n], A bf16 [M][K], Bt bf16 [N][K].
// BK=64, XOR-swizzled LDS staging. MODE 1: fp32 out [M][N] direct.
template <int MODE>
__global__ __launch_bounds__(256) void gemm_bt_kernel(
    const short* __restrict__ A, const short* __restrict__ Bt,
    const float* __restrict__ bias, float* __restrict__ outf,
    short* __restrict__ oq, short* __restrict__ ok, short* __restrict__ ovt,
    int M, int N, int K) {
  __shared__ short slds[16384];  // As[128][64] + Bs[128][64] = 32KB
  short* As = slds;
  short* Bs = slds + 8192;
  const int m0 = blockIdx.y * 128, n0 = blockIdx.x * 128;
  const int lane = threadIdx.x & 63, wave = threadIdx.x >> 6;
  const int quad = lane >> 4, l16 = lane & 15;
  const int wm = (wave >> 1) * 64, wn = (wave & 1) * 64;

  const int row_off = lane >> 3;                 // 0..7
  const int segsw = ((lane & 7) ^ row_off) * 8;  // XOR-swizzled global seg
  const short* Ag = A + (size_t)(m0 + wave * 32 + row_off) * K + segsw;
  const short* Bg = Bt + (size_t)(n0 + wave * 32 + row_off) * K + segsw;

  f32x4 acc[4][4] = {};

  for (int k0 = 0; k0 < K; k0 += 64) {
#pragma unroll
    for (int g = 0; g < 4; ++g) {
      gld_lds16(Ag + (size_t)(g * 8) * K + k0, &As[(wave * 32 + g * 8) * 64]);
      gld_lds16(Bg + (size_t)(g * 8) * K + k0, &Bs[(wave * 32 + g * 8) * 64]);
    }
    __syncthreads();
#pragma unroll
    for (int kh = 0; kh < 2; ++kh) {
      short8 a[4], b[4];
#pragma unroll
      for (int t = 0; t < 4; ++t) {
        const int R = wm + t * 16 + l16;
        a[t] = *(const short8*)&As[R * 64 + (((kh * 4 + quad) ^ (R & 7)) * 8)];
      }
#pragma unroll
      for (int t = 0; t < 4; ++t) {
        const int R = wn + t * 16 + l16;
        b[t] = *(const short8*)&Bs[R * 64 + (((kh * 4 + quad) ^ (R & 7)) * 8)];
      }
#pragma unroll
      for (int mt = 0; mt < 4; ++mt)
#pragma unroll
        for (int nt = 0; nt < 4; ++nt)
          acc[mt][nt] = __builtin_amdgcn_mfma_f32_16x16x32_bf16(
              a[mt], b[nt], acc[mt][nt], 0, 0, 0);
    }
    __syncthreads();
  }

  float bv[4];
#pragma unroll
  for (int nt = 0; nt < 4; ++nt) bv[nt] = bias[n0 + wn + nt * 16 + l16];

  if (MODE == 1) {
#pragma unroll
    for (int mt = 0; mt < 4; ++mt)
#pragma unroll
      for (int nt = 0; nt < 4; ++nt) {
        const int n = n0 + wn + nt * 16 + l16;
#pragma unroll
        for (int r = 0; r < 4; ++r) {
          const int m = m0 + wm + mt * 16 + quad * 4 + r;
          outf[(size_t)m * N + n] = acc[mt][nt][r] + bv[nt];
        }
      }
  }
}

// --------------------------- flash attention -----------------------------
// (round-5 version, unchanged)
__global__ __launch_bounds__(256, 6) void attn_kernel(
    const short* __restrict__ q, const short* __restrict__ k,
    const short* __restrict__ vt, short* __restrict__ y) {
  __shared__ short Ks[64 * 64];
  __shared__ short Vs[64 * 64];
  __shared__ short Ps[4][16 * 72];
  const int lane = threadIdx.x & 63, wave = threadIdx.x >> 6;
  const int quad = lane >> 4, l16 = lane & 15;
  const int g = blockIdx.x;
  const int bh = g & 63;
  const int j = 31 - (g >> 6);  // big blocks dispatched first
  const int b_ = bh >> 4, h = bh & 15;
  const int q0 = j * 64 + wave * 16;

  const short* qbh = q + (size_t)bh * 2048 * 64;
  const short* kbh = k + (size_t)bh * 2048 * 64;
  const short* vbh = vt + (size_t)bh * 64 * 2048;
  short* Pw = Ps[wave];

  const short8 qf0 = *(const short8*)&qbh[(q0 + l16) * 64 + quad * 8];
  const short8 qf1 = *(const short8*)&qbh[(q0 + l16) * 64 + 32 + quad * 8];

  short8 ones;
#pragma unroll
  for (int i = 0; i < 8; ++i) ones[i] = (short)0x3F80;  // bf16 1.0

  f32x4 O[4] = {};
  f32x4 lacc = {};

  const int srow = lane >> 3;
  const int scol = ((lane & 7) ^ srow) * 8;
  const int r0s = wave * 16;

#pragma unroll 1
  for (int c = 0; c <= j; ++c) {
    const int kt0 = c * 64;
    gld_lds16(kbh + (size_t)(kt0 + r0s + srow) * 64 + scol, &Ks[r0s * 64]);
    gld_lds16(kbh + (size_t)(kt0 + r0s + 8 + srow) * 64 + scol, &Ks[(r0s + 8) * 64]);
    gld_lds16(vbh + (size_t)(r0s + srow) * 2048 + kt0 + scol, &Vs[r0s * 64]);
    gld_lds16(vbh + (size_t)(r0s + 8 + srow) * 2048 + kt0 + scol, &Vs[(r0s + 8) * 64]);
    __syncthreads();

    const int sw = l16 & 7;
    f32x4 sc4[4];
#pragma unroll
    for (int cf = 0; cf < 4; ++cf) {
      const int row = cf * 16 + l16;
      const short8 kfa = *(const short8*)&Ks[row * 64 + ((quad ^ sw) * 8)];
      const short8 kfb = *(const short8*)&Ks[row * 64 + (((quad + 4) ^ sw) * 8)];
      f32x4 z = {};
      z = __builtin_amdgcn_mfma_f32_16x16x32_bf16(qf0, kfa, z, 0, 0, 0);
      z = __builtin_amdgcn_mfma_f32_16x16x32_bf16(qf1, kfb, z, 0, 0, 0);
      sc4[cf] = z;
    }

    if (c == j) {
#pragma unroll
      for (int cf = 0; cf < 4; ++cf) {
        const int col = kt0 + cf * 16 + l16;
#pragma unroll
        for (int r = 0; r < 4; ++r) {
          const int rowg = q0 + quad * 4 + r;
          float e = exp2_fast(sc4[cf][r]);
          e = (col > rowg) ? 0.f : e;
          Pw[(quad * 4 + r) * 72 + cf * 16 + l16] = f2bf(e);
        }
      }
    } else {
#pragma unroll
      for (int cf = 0; cf < 4; ++cf)
#pragma unroll
        for (int r = 0; r < 4; ++r)
          Pw[(quad * 4 + r) * 72 + cf * 16 + l16] = f2bf(exp2_fast(sc4[cf][r]));
    }
    asm volatile("s_waitcnt lgkmcnt(0)" ::: "memory");
    const short8 pf0 = *(const short8*)&Pw[l16 * 72 + quad * 8];
    const short8 pf1 = *(const short8*)&Pw[l16 * 72 + 32 + quad * 8];

    lacc = __builtin_amdgcn_mfma_f32_16x16x32_bf16(pf0, ones, lacc, 0, 0, 0);
    lacc = __builtin_amdgcn_mfma_f32_16x16x32_bf16(pf1, ones, lacc, 0, 0, 0);

#pragma unroll
    for (int dt = 0; dt < 4; ++dt) {
      const int d = dt * 16 + l16;
      const short8 vf0 = *(const short8*)&Vs[d * 64 + ((quad ^ sw) * 8)];
      const short8 vf1 = *(const short8*)&Vs[d * 64 + (((quad + 4) ^ sw) * 8)];
      O[dt] = __builtin_amdgcn_mfma_f32_16x16x32_bf16(pf0, vf0, O[dt], 0, 0, 0);
      O[dt] = __builtin_amdgcn_mfma_f32_16x16x32_bf16(pf1, vf1, O[dt], 0, 0, 0);
    }
    __syncthreads();
  }

  float inv[4];
#pragma unroll
  for (int r = 0; r < 4; ++r) inv[r] = 1.0f / lacc[r];
#pragma unroll
  for (int dt = 0; dt < 4; ++dt) {
    const int d = dt * 16 + l16;
#pragma unroll
    for (int r = 0; r < 4; ++r) {
      const int t_ = q0 + quad * 4 + r;
      y[((size_t)b_ * 2048 + t_) * 1024 + h * 64 + d] = f2bf(O[dt][r] * inv[r]);
    }
  }
}

// -------------------------------------------------------------------------
extern "C" void kernel_launch(void* const* d_in, const int* in_sizes, int n_in,
                              void* d_out, int out_size, void* d_ws, size_t ws_size,
                              hipStream_t stream) {
  const float* x      = (const float*)d_in[0];
  const float* w_attn = (const float*)d_in[1];
  const float* b_attn = (const float*)d_in[2];
  const float* w_proj = (const float*)d_in[3];
  const float* b_proj = (const float*)d_in[4];
  float* out = (float*)d_out;

  short* xb  = (short*)d_ws;                    // [8192][1024]
  short* wTa = xb + (size_t)8192 * 1024;        // [3072][1024]
  short* wTp = wTa + (size_t)3072 * 1024;       // [1024][1024]
  short* qb  = wTp + (size_t)1024 * 1024;       // [64][2048][64]
  short* kb  = qb + (size_t)64 * 2048 * 64;     // [64][2048][64]
  short* vtb = kb + (size_t)64 * 2048 * 64;     // [64][64][2048]
  short* yb  = vtb + (size_t)64 * 2048 * 64;    // [8192][1024]

  static int lds_attr_done = 0;
  if (!lds_attr_done) {
    (void)hipFuncSetAttribute(reinterpret_cast<const void*>(qkv_gemm_kernel),
                              hipFuncAttributeMaxDynamicSharedMemorySize,
                              131072);
    lds_attr_done = 1;
  }

  cast_bf16_kernel<<<8192, 256, 0, stream>>>(x, xb, 8192 * 1024 / 4);
  transpose_cast_kernel<<<dim3(96, 32), 256, 0, stream>>>(w_attn, wTa, 1024, 3072);
  transpose_cast_kernel<<<dim3(32, 32), 256, 0, stream>>>(w_proj, wTp, 1024, 1024);

  qkv_gemm_kernel<<<384, 512, 131072, stream>>>(
      xb, wTa, b_attn, qb, kb, vtb, 8192, 3072, 1024);

  attn_kernel<<<2048, 256, 0, stream>>>(qb, kb, vtb, yb);

  gemm_bt_kernel<1><<<dim3(8, 64), 256, 0, stream>>>(
      yb, wTp, b_proj, out, nullptr, nullptr, nullptr, 8192, 1024, 1024);
}

// Round 4
// 244.670 us; speedup vs baseline: 1.0241x; 1.0241x over previous
//
#include <hip/hip_runtime.h>
#include <cmath>

// Round 11: QKV GEMM K-loop restructured to ONE barrier per K-tile with a
// kh-split two-window body. r9/r10 proved the stall is structural: per-tile
// 5662cy == LDS-read(2258) + MFMA(2355) + DMA(512) + 8 barriers(~1040) with
// ZERO pipe overlap (resident MfmaUtil 36% + LDS 40% + VALU 23% ~= 100%).
// New body per tile t:
//   [12 dsr kh0 | stage tile t+1 -> OTHER buffer]  lgkm0  32 indep MFMA
//   [12 dsr kh1]                                   lgkm0  32 indep MFMA
//   vmcnt(0)  s_barrier
// Safety with 1 barrier: stage never targets the buffer being read; each
// wave's last reads of buf(t) precede its own lgkm0 which precedes its
// barrier arrival; re-staging of that buffer is issued only after that
// barrier by construction -> no DMA/read race. Wave skew is now allowed
// within a tile -> ds_read service overlaps MFMA drain (kh-split makes all
// 32 MFMAs per window chain-free -> fast issue, deep queue). Prefetch depth
// 1 tile: per-wave vmcnt(0) has ~2500cy slack >> 900cy HBM latency.
// Epilogue/attn/proj/casts unchanged. B=4 T=2048 C=1024 H=16 hd=64.

typedef short short8 __attribute__((ext_vector_type(8)));
typedef short short4v __attribute__((ext_vector_type(4)));
typedef float f32x4 __attribute__((ext_vector_type(4)));

__device__ __forceinline__ short f2bf(float f) {
  unsigned u = __builtin_bit_cast(unsigned, f);
  u = (u + 0x7fffu + ((u >> 16) & 1u)) >> 16;   // RNE; inputs are finite
  return (short)u;
}

__device__ __forceinline__ float exp2_fast(float x) {
  float r;
  asm("v_exp_f32 %0, %1" : "=v"(r) : "v"(x));
  return r;
}

__device__ __forceinline__ void gld_lds16(const void* g, void* l) {
  __builtin_amdgcn_global_load_lds(
      (__attribute__((address_space(1))) void*)g,
      (__attribute__((address_space(3))) void*)l,
      16, 0, 0);
}

// raw barrier, opaque to SIInsertWaitcnts (no implicit counter drain)
__device__ __forceinline__ void barx() {
  asm volatile("s_barrier" ::: "memory");
}

// asm ds_read_b128 at byte address + compile-time offset (waitcnt-opaque)
template <int IMM>
__device__ __forceinline__ short8 dsr(int addr) {
  short8 d;
  asm volatile("ds_read_b128 %0, %1 offset:%2"
               : "=v"(d) : "v"(addr), "n"(IMM));
  return d;
}

// wait own-wave ds_reads; sched_barrier stops MFMA hoisting past it (rule #18)
#define WAITL()                                       \
  asm volatile("s_waitcnt lgkmcnt(0)" ::: "memory");  \
  __builtin_amdgcn_sched_barrier(0);

// ---------------- cast fp32 -> bf16 bits (4 elems/thread) ----------------
__global__ void cast_bf16_kernel(const float* __restrict__ in,
                                 short* __restrict__ out, int n4) {
  int i = blockIdx.x * blockDim.x + threadIdx.x;
  if (i < n4) {
    const float4 v = ((const float4*)in)[i];
    short4v o;
    o.x = f2bf(v.x); o.y = f2bf(v.y); o.z = f2bf(v.z); o.w = f2bf(v.w);
    ((short4v*)out)[i] = o;
  }
}

// ------------- transpose+cast: fp32 [R][C] -> bf16 [C][R] ----------------
__global__ void transpose_cast_kernel(const float* __restrict__ in,
                                      short* __restrict__ out, int R, int C) {
  __shared__ float tile[32][33];
  int c0 = blockIdx.x * 32, r0 = blockIdx.y * 32;
  int tx = threadIdx.x & 31, tg = threadIdx.x >> 5;
#pragma unroll
  for (int i = 0; i < 4; ++i) {
    int r = tg * 4 + i;
    tile[r][tx] = in[(size_t)(r0 + r) * C + c0 + tx];
  }
  __syncthreads();
#pragma unroll
  for (int i = 0; i < 4; ++i) {
    int c = tg * 4 + i;
    out[(size_t)(c0 + c) * R + r0 + tx] = f2bf(tile[tx][c]);
  }
}

// --------------- QKV GEMM: 256x256 tile, 8-wave, 1-barrier/tile ----------
// C = A[M][K] * Bt[N][K]^T + bias; outputs split to q/k (bf16 [bh][t][d],
// q scaled by log2e/8) and vT (bf16 [bh][d][t]). M=8192 N=3072 K=1024.
// 512 threads = 8 waves (2M x 4N), per-wave C = 128x64 (8x4 16x16 frags).
// LDS: dbuf x (A 256x64 + B 256x64) bf16 = 128KB (dynamic). XOR-swizzled
// via pre-swizzled global source (linear LDS dest, gld_lds requirement).

__global__ __launch_bounds__(512, 2) void qkv_gemm_kernel(
    const short* __restrict__ A, const short* __restrict__ Bt,
    const float* __restrict__ bias,
    short* __restrict__ oq, short* __restrict__ ok, short* __restrict__ ovt,
    int M, int N, int K) {
  extern __shared__ short lds[];
  const int NT = K >> 6;  // 16 K-tiles
  const int lane = threadIdx.x & 63, wave = threadIdx.x >> 6;
  const int quad = lane >> 4, l16 = lane & 15;
  const int wm2 = wave >> 2, wn4 = wave & 3;

  // bijective XCD swizzle (grid % 8 == 0); n varies fastest within an XCD.
  const int nbn = N >> 8;
  const int swz = (blockIdx.x & 7) * ((int)gridDim.x >> 3) + (blockIdx.x >> 3);
  const int m0 = (swz / nbn) * 256, n0 = (swz % nbn) * 256;

  // staging: per gld, wave w covers 8 rows (w*8 + lane>>3) x 8 16B segs,
  // global seg XOR-pre-swizzled so linear LDS dest yields swizzled layout.
  const int r8 = lane >> 3;
  const int sw8 = ((lane & 7) ^ r8) * 8;
  const short* Ab0 = A + (size_t)(m0 + wave * 8 + r8) * K + sw8;
  const short* Bb0 = Bt + (size_t)(n0 + wave * 8 + r8) * K + sw8;
  short* ldsw = lds + wave * 512;

  auto stage = [&](int t, int mat, int rA, int rB) {
    const short* g = (mat ? Bb0 : Ab0) + t * 64;
    short* d = ldsw + (t & 1) * 32768 + mat * 16384;
    gld_lds16(g + (size_t)rA * K, d + rA * 64);
    gld_lds16(g + (size_t)rB * K, d + rB * 64);
  };

  // fragment read base addresses (bytes): swizzle term is frag-invariant.
  // frag addr = base + (t&1)*65536 + frag_row16*2048, row stride 128B.
  const int swz0 = ((0 + quad) ^ (l16 & 7)) * 16;  // kh=0
  const int swz1 = ((4 + quad) ^ (l16 & 7)) * 16;  // kh=1
  const int baseA0 = wm2 * 16384 + l16 * 128 + swz0;
  const int baseA1 = wm2 * 16384 + l16 * 128 + swz1;
  const int baseB0 = 32768 + wn4 * 8192 + l16 * 128 + swz0;
  const int baseB1 = 32768 + wn4 * 8192 + l16 * 128 + swz1;

  f32x4 acc[8][4] = {};

  // prologue: stage tile 0 fully (4 chunks = 8 gld/thread)
  stage(0, 1, 0, 64);
  stage(0, 1, 128, 192);
  stage(0, 0, 0, 128);
  stage(0, 0, 64, 192);
  asm volatile("s_waitcnt vmcnt(0)" ::: "memory");
  barx();

#pragma unroll 1
  for (int t = 0; t < NT; ++t) {
    const int vb = (t & 1) << 16;
    const int aA0 = baseA0 + vb, aA1 = baseA1 + vb;
    const int aB0 = baseB0 + vb, aB1 = baseB1 + vb;
    short8 a[8], b[4];

    // ---- window A: kh0 frags; stage ALL of tile t+1 (other buffer) ----
    b[0] = dsr<0>(aB0);     b[1] = dsr<2048>(aB0);
    b[2] = dsr<4096>(aB0);  b[3] = dsr<6144>(aB0);
    a[0] = dsr<0>(aA0);     a[1] = dsr<2048>(aA0);
    a[2] = dsr<4096>(aA0);  a[3] = dsr<6144>(aA0);
    a[4] = dsr<8192>(aA0);  a[5] = dsr<10240>(aA0);
    a[6] = dsr<12288>(aA0); a[7] = dsr<14336>(aA0);
    if (t + 1 < NT) {
      stage(t + 1, 1, 0, 64);
      stage(t + 1, 1, 128, 192);
      stage(t + 1, 0, 0, 128);
      stage(t + 1, 0, 64, 192);
    }
    WAITL()
    __builtin_amdgcn_s_setprio(1);
#pragma unroll
    for (int i_ = 0; i_ < 8; ++i_)
#pragma unroll
      for (int n_ = 0; n_ < 4; ++n_)
        acc[i_][n_] = __builtin_amdgcn_mfma_f32_16x16x32_bf16(
            a[i_], b[n_], acc[i_][n_], 0, 0, 0);
    __builtin_amdgcn_s_setprio(0);

    // ---- window B: kh1 frags (reads overlap window-A MFMA drain) ----
    b[0] = dsr<0>(aB1);     b[1] = dsr<2048>(aB1);
    b[2] = dsr<4096>(aB1);  b[3] = dsr<6144>(aB1);
    a[0] = dsr<0>(aA1);     a[1] = dsr<2048>(aA1);
    a[2] = dsr<4096>(aA1);  a[3] = dsr<6144>(aA1);
    a[4] = dsr<8192>(aA1);  a[5] = dsr<10240>(aA1);
    a[6] = dsr<12288>(aA1); a[7] = dsr<14336>(aA1);
    WAITL()
    __builtin_amdgcn_s_setprio(1);
#pragma unroll
    for (int i_ = 0; i_ < 8; ++i_)
#pragma unroll
      for (int n_ = 0; n_ < 4; ++n_)
        acc[i_][n_] = __builtin_amdgcn_mfma_f32_16x16x32_bf16(
            a[i_], b[n_], acc[i_][n_], 0, 0, 0);
    __builtin_amdgcn_s_setprio(0);

    // own DMAs for tile t+1 must land before any wave crosses the barrier
    if (t + 1 < NT)
      asm volatile("s_waitcnt vmcnt(0)" ::: "memory");
    barx();
  }

  // ------------------------------ epilogue -------------------------------
  const int sec = n0 >> 10;                 // 0=q 1=k 2=v
  const int h0 = (n0 & 1023) >> 6;
  const float scale = (sec == 0) ? 0.18033688f : 1.0f;  // log2e/8 into q
  float bv[4];
#pragma unroll
  for (int n_ = 0; n_ < 4; ++n_) bv[n_] = bias[n0 + wn4 * 64 + n_ * 16 + l16];
  const int b_ = m0 >> 11, t0 = m0 & 2047;

  if (sec < 2) {
    // two passes over M-halves; Cs[128][264] bf16 (stride 528B: uniform banks)
    short* dst = (sec == 0) ? oq : ok;
#pragma unroll 1
    for (int p = 0; p < 2; ++p) {
      if (wm2 == p) {
#pragma unroll
        for (int mt = 0; mt < 8; ++mt)
#pragma unroll
          for (int n_ = 0; n_ < 4; ++n_) {
            const int col = wn4 * 64 + n_ * 16 + l16;
#pragma unroll
            for (int r = 0; r < 4; ++r)
              lds[(mt * 16 + quad * 4 + r) * 264 + col] =
                  f2bf((acc[mt][n_][r] + bv[n_]) * scale);
          }
      }
      __syncthreads();
      // wave w: head w&3, row-group w>>2; each iter = 8 t-rows x 64 d = 1KB
      const int hl = wave & 3, rg = wave >> 2;
      const short* sp = &lds[(rg * 64 + r8) * 264 + hl * 64 + (lane & 7) * 8];
      short* gp = dst +
          ((size_t)(b_ * 16 + h0 + hl) * 2048 + t0 + p * 128 + rg * 64 + r8) * 64 +
          (lane & 7) * 8;
#pragma unroll
      for (int i = 0; i < 8; ++i)
        *(short8*)(gp + (size_t)i * 512) = *(const short8*)(sp + i * 8 * 264);
      __syncthreads();
    }
  } else {
    // v: transposed repack; Cs[256 cols][136] bf16 per pass
#pragma unroll 1
    for (int p = 0; p < 2; ++p) {
      if (wm2 == p) {
#pragma unroll
        for (int mt = 0; mt < 8; ++mt)
#pragma unroll
          for (int n_ = 0; n_ < 4; ++n_) {
            const int col = wn4 * 64 + n_ * 16 + l16;
#pragma unroll
            for (int r = 0; r < 4; ++r)
              lds[col * 136 + mt * 16 + quad * 4 + r] =
                  f2bf(acc[mt][n_][r] + bv[n_]);
          }
      }
      __syncthreads();
      // wave w covers cols [w*32,+32): iter = 4 d-cols x 128 t = 4x256B
      const int cw = wave * 32 + (lane >> 4);
#pragma unroll
      for (int i = 0; i < 8; ++i) {
        const int c = cw + i * 4;
        const int bh = b_ * 16 + h0 + (c >> 6), d = c & 63;
        *(short8*)(ovt + ((size_t)bh * 64 + d) * 2048 + t0 + p * 128 +
                   (lane & 15) * 8) =
            *(const short8*)&lds[c * 136 + (lane & 15) * 8];
      }
      __syncthreads();
    }
  }
}

// ------------------------- proj GEMM (unchanged) -------------------------
// C[m][n] = sum_k A[m][k]*B[k][n] + bias[n], A bf16 [M][K], Bt bf16 [N][K].
// BK=64, XOR-swizzled LDS staging. MODE 1: fp32 out [M][N] direct.
template <int MODE>
__global__ __launch_bounds__(256) void gemm_bt_kernel(
    const short* __restrict__ A, const short* __restrict__ Bt,
    const float* __restrict__ bias, float* __restrict__ outf,
    short* __restrict__ oq, short* __restrict__ ok, short* __restrict__ ovt,
    int M, int N, int K) {
  __shared__ short slds[16384];  // As[128][64] + Bs[128][64] = 32KB
  short* As = slds;
  short* Bs = slds + 8192;
  const int m0 = blockIdx.y * 128, n0 = blockIdx.x * 128;
  const int lane = threadIdx.x & 63, wave = threadIdx.x >> 6;
  const int quad = lane >> 4, l16 = lane & 15;
  const int wm = (wave >> 1) * 64, wn = (wave & 1) * 64;

  const int row_off = lane >> 3;                 // 0..7
  const int segsw = ((lane & 7) ^ row_off) * 8;  // XOR-swizzled global seg
  const short* Ag = A + (size_t)(m0 + wave * 32 + row_off) * K + segsw;
  const short* Bg = Bt + (size_t)(n0 + wave * 32 + row_off) * K + segsw;

  f32x4 acc[4][4] = {};

  for (int k0 = 0; k0 < K; k0 += 64) {
#pragma unroll
    for (int g = 0; g < 4; ++g) {
      gld_lds16(Ag + (size_t)(g * 8) * K + k0, &As[(wave * 32 + g * 8) * 64]);
      gld_lds16(Bg + (size_t)(g * 8) * K + k0, &Bs[(wave * 32 + g * 8) * 64]);
    }
    __syncthreads();
#pragma unroll
    for (int kh = 0; kh < 2; ++kh) {
      short8 a[4], b[4];
#pragma unroll
      for (int t = 0; t < 4; ++t) {
        const int R = wm + t * 16 + l16;
        a[t] = *(const short8*)&As[R * 64 + (((kh * 4 + quad) ^ (R & 7)) * 8)];
      }
#pragma unroll
      for (int t = 0; t < 4; ++t) {
        const int R = wn + t * 16 + l16;
        b[t] = *(const short8*)&Bs[R * 64 + (((kh * 4 + quad) ^ (R & 7)) * 8)];
      }
#pragma unroll
      for (int mt = 0; mt < 4; ++mt)
#pragma unroll
        for (int nt = 0; nt < 4; ++nt)
          acc[mt][nt] = __builtin_amdgcn_mfma_f32_16x16x32_bf16(
              a[mt], b[nt], acc[mt][nt], 0, 0, 0);
    }
    __syncthreads();
  }

  float bv[4];
#pragma unroll
  for (int nt = 0; nt < 4; ++nt) bv[nt] = bias[n0 + wn + nt * 16 + l16];

  if (MODE == 1) {
#pragma unroll
    for (int mt = 0; mt < 4; ++mt)
#pragma unroll
      for (int nt = 0; nt < 4; ++nt) {
        const int n = n0 + wn + nt * 16 + l16;
#pragma unroll
        for (int r = 0; r < 4; ++r) {
          const int m = m0 + wm + mt * 16 + quad * 4 + r;
          outf[(size_t)m * N + n] = acc[mt][nt][r] + bv[nt];
        }
      }
  }
}

// --------------------------- flash attention -----------------------------
// (round-5 version, unchanged)
__global__ __launch_bounds__(256, 6) void attn_kernel(
    const short* __restrict__ q, const short* __restrict__ k,
    const short* __restrict__ vt, short* __restrict__ y) {
  __shared__ short Ks[64 * 64];
  __shared__ short Vs[64 * 64];
  __shared__ short Ps[4][16 * 72];
  const int lane = threadIdx.x & 63, wave = threadIdx.x >> 6;
  const int quad = lane >> 4, l16 = lane & 15;
  const int g = blockIdx.x;
  const int bh = g & 63;
  const int j = 31 - (g >> 6);  // big blocks dispatched first
  const int b_ = bh >> 4, h = bh & 15;
  const int q0 = j * 64 + wave * 16;

  const short* qbh = q + (size_t)bh * 2048 * 64;
  const short* kbh = k + (size_t)bh * 2048 * 64;
  const short* vbh = vt + (size_t)bh * 64 * 2048;
  short* Pw = Ps[wave];

  const short8 qf0 = *(const short8*)&qbh[(q0 + l16) * 64 + quad * 8];
  const short8 qf1 = *(const short8*)&qbh[(q0 + l16) * 64 + 32 + quad * 8];

  short8 ones;
#pragma unroll
  for (int i = 0; i < 8; ++i) ones[i] = (short)0x3F80;  // bf16 1.0

  f32x4 O[4] = {};
  f32x4 lacc = {};

  const int srow = lane >> 3;
  const int scol = ((lane & 7) ^ srow) * 8;
  const int r0s = wave * 16;

#pragma unroll 1
  for (int c = 0; c <= j; ++c) {
    const int kt0 = c * 64;
    gld_lds16(kbh + (size_t)(kt0 + r0s + srow) * 64 + scol, &Ks[r0s * 64]);
    gld_lds16(kbh + (size_t)(kt0 + r0s + 8 + srow) * 64 + scol, &Ks[(r0s + 8) * 64]);
    gld_lds16(vbh + (size_t)(r0s + srow) * 2048 + kt0 + scol, &Vs[r0s * 64]);
    gld_lds16(vbh + (size_t)(r0s + 8 + srow) * 2048 + kt0 + scol, &Vs[(r0s + 8) * 64]);
    __syncthreads();

    const int sw = l16 & 7;
    f32x4 sc4[4];
#pragma unroll
    for (int cf = 0; cf < 4; ++cf) {
      const int row = cf * 16 + l16;
      const short8 kfa = *(const short8*)&Ks[row * 64 + ((quad ^ sw) * 8)];
      const short8 kfb = *(const short8*)&Ks[row * 64 + (((quad + 4) ^ sw) * 8)];
      f32x4 z = {};
      z = __builtin_amdgcn_mfma_f32_16x16x32_bf16(qf0, kfa, z, 0, 0, 0);
      z = __builtin_amdgcn_mfma_f32_16x16x32_bf16(qf1, kfb, z, 0, 0, 0);
      sc4[cf] = z;
    }

    if (c == j) {
#pragma unroll
      for (int cf = 0; cf < 4; ++cf) {
        const int col = kt0 + cf * 16 + l16;
#pragma unroll
        for (int r = 0; r < 4; ++r) {
          const int rowg = q0 + quad * 4 + r;
          float e = exp2_fast(sc4[cf][r]);
          e = (col > rowg) ? 0.f : e;
          Pw[(quad * 4 + r) * 72 + cf * 16 + l16] = f2bf(e);
        }
      }
    } else {
#pragma unroll
      for (int cf = 0; cf < 4; ++cf)
#pragma unroll
        for (int r = 0; r < 4; ++r)
          Pw[(quad * 4 + r) * 72 + cf * 16 + l16] = f2bf(exp2_fast(sc4[cf][r]));
    }
    asm volatile("s_waitcnt lgkmcnt(0)" ::: "memory");
    const short8 pf0 = *(const short8*)&Pw[l16 * 72 + quad * 8];
    const short8 pf1 = *(const short8*)&Pw[l16 * 72 + 32 + quad * 8];

    lacc = __builtin_amdgcn_mfma_f32_16x16x32_bf16(pf0, ones, lacc, 0, 0, 0);
    lacc = __builtin_amdgcn_mfma_f32_16x16x32_bf16(pf1, ones, lacc, 0, 0, 0);

#pragma unroll
    for (int dt = 0; dt < 4; ++dt) {
      const int d = dt * 16 + l16;
      const short8 vf0 = *(const short8*)&Vs[d * 64 + ((quad ^ sw) * 8)];
      const short8 vf1 = *(const short8*)&Vs[d * 64 + (((quad + 4) ^ sw) * 8)];
      O[dt] = __builtin_amdgcn_mfma_f32_16x16x32_bf16(pf0, vf0, O[dt], 0, 0, 0);
      O[dt] = __builtin_amdgcn_mfma_f32_16x16x32_bf16(pf1, vf1, O[dt], 0, 0, 0);
    }
    __syncthreads();
  }

  float inv[4];
#pragma unroll
  for (int r = 0; r < 4; ++r) inv[r] = 1.0f / lacc[r];
#pragma unroll
  for (int dt = 0; dt < 4; ++dt) {
    const int d = dt * 16 + l16;
#pragma unroll
    for (int r = 0; r < 4; ++r) {
      const int t_ = q0 + quad * 4 + r;
      y[((size_t)b_ * 2048 + t_) * 1024 + h * 64 + d] = f2bf(O[dt][r] * inv[r]);
    }
  }
}

// -------------------------------------------------------------------------
extern "C" void kernel_launch(void* const* d_in, const int* in_sizes, int n_in,
                              void* d_out, int out_size, void* d_ws, size_t ws_size,
                              hipStream_t stream) {
  const float* x      = (const float*)d_in[0];
  const float* w_attn = (const float*)d_in[1];
  const float* b_attn = (const float*)d_in[2];
  const float* w_proj = (const float*)d_in[3];
  const float* b_proj = (const float*)d_in[4];
  float* out = (float*)d_out;

  short* xb  = (short*)d_ws;                    // [8192][1024]
  short* wTa = xb + (size_t)8192 * 1024;        // [3072][1024]
  short* wTp = wTa + (size_t)3072 * 1024;       // [1024][1024]
  short* qb  = wTp + (size_t)1024 * 1024;       // [64][2048][64]
  short* kb  = qb + (size_t)64 * 2048 * 64;     // [64][2048][64]
  short* vtb = kb + (size_t)64 * 2048 * 64;     // [64][64][2048]
  short* yb  = vtb + (size_t)64 * 2048 * 64;    // [8192][1024]

  static int lds_attr_done = 0;
  if (!lds_attr_done) {
    (void)hipFuncSetAttribute(reinterpret_cast<const void*>(qkv_gemm_kernel),
                              hipFuncAttributeMaxDynamicSharedMemorySize,
                              131072);
    lds_attr_done = 1;
  }

  cast_bf16_kernel<<<8192, 256, 0, stream>>>(x, xb, 8192 * 1024 / 4);
  transpose_cast_kernel<<<dim3(96, 32), 256, 0, stream>>>(w_attn, wTa, 1024, 3072);
  transpose_cast_kernel<<<dim3(32, 32), 256, 0, stream>>>(w_proj, wTp, 1024, 1024);

  qkv_gemm_kernel<<<384, 512, 131072, stream>>>(
      xb, wTa, b_attn, qb, kb, vtb, 8192, 3072, 1024);

  attn_kernel<<<2048, 256, 0, stream>>>(qb, kb, vtb, yb);

  gemm_bt_kernel<1><<<dim3(8, 64), 256, 0, stream>>>(
      yb, wTp, b_proj, out, nullptr, nullptr, nullptr, 8192, 1024, 1024);
}

// Round 5
// 242.672 us; speedup vs baseline: 1.0325x; 1.0082x over previous
//
#include <hip/hip_runtime.h>
#include <cmath>

// Round 12: QKV GEMM re-tiled 256x256 -> 128x256 with a true within-wave
// software pipeline. r11 analysis: per-tile 5145cy == lockstep whole-CU
// bursts readsA(768) -> mfmaA(1229) -> readsB(768) -> mfmaB(1229) + sync;
// port and MFMA pipe never overlap because window-B reads are issued after
// window-A MFMAs and a second register window didn't fit (248/256 VGPR).
// 128x256 tile halves acc to 64 VGPR -> both kh windows fit in regs:
//   issue 8 dsr kh0 | stage 6 DMA | issue 8 dsr kh1
//   lgkmcnt(8)  [DS ops retire in-order -> kh0 ready]  16 MFMA kh0
//   lgkmcnt(0)                                         16 MFMA kh1
//   vmcnt(0)  s_barrier
// kh1 reads are serviced by the LDS port underneath the kh0 MFMAs.
// Grid: 64 m-tiles x 12 n-tiles = 768 blocks = 3 exactly-full rounds
// (kills r11's 25% packing loss). Epilogue single-pass (<=70KB of 96KB LDS).
// Attn/proj/casts unchanged. B=4 T=2048 C=1024 H=16 hd=64.

typedef short short8 __attribute__((ext_vector_type(8)));
typedef short short4v __attribute__((ext_vector_type(4)));
typedef float f32x4 __attribute__((ext_vector_type(4)));

__device__ __forceinline__ short f2bf(float f) {
  unsigned u = __builtin_bit_cast(unsigned, f);
  u = (u + 0x7fffu + ((u >> 16) & 1u)) >> 16;   // RNE; inputs are finite
  return (short)u;
}

__device__ __forceinline__ float exp2_fast(float x) {
  float r;
  asm("v_exp_f32 %0, %1" : "=v"(r) : "v"(x));
  return r;
}

__device__ __forceinline__ void gld_lds16(const void* g, void* l) {
  __builtin_amdgcn_global_load_lds(
      (__attribute__((address_space(1))) void*)g,
      (__attribute__((address_space(3))) void*)l,
      16, 0, 0);
}

// raw barrier, opaque to SIInsertWaitcnts (no implicit counter drain)
__device__ __forceinline__ void barx() {
  asm volatile("s_barrier" ::: "memory");
}

// asm ds_read_b128 at byte address + compile-time offset (waitcnt-opaque)
template <int IMM>
__device__ __forceinline__ short8 dsr(int addr) {
  short8 d;
  asm volatile("ds_read_b128 %0, %1 offset:%2"
               : "=v"(d) : "v"(addr), "n"(IMM));
  return d;
}

// counted lgkm wait; sched_barrier stops MFMA motion across it (rule #18)
#define WAITLN(n)                                          \
  asm volatile("s_waitcnt lgkmcnt(" #n ")" ::: "memory");  \
  __builtin_amdgcn_sched_barrier(0);

// ---------------- cast fp32 -> bf16 bits (4 elems/thread) ----------------
__global__ void cast_bf16_kernel(const float* __restrict__ in,
                                 short* __restrict__ out, int n4) {
  int i = blockIdx.x * blockDim.x + threadIdx.x;
  if (i < n4) {
    const float4 v = ((const float4*)in)[i];
    short4v o;
    o.x = f2bf(v.x); o.y = f2bf(v.y); o.z = f2bf(v.z); o.w = f2bf(v.w);
    ((short4v*)out)[i] = o;
  }
}

// ------------- transpose+cast: fp32 [R][C] -> bf16 [C][R] ----------------
__global__ void transpose_cast_kernel(const float* __restrict__ in,
                                      short* __restrict__ out, int R, int C) {
  __shared__ float tile[32][33];
  int c0 = blockIdx.x * 32, r0 = blockIdx.y * 32;
  int tx = threadIdx.x & 31, tg = threadIdx.x >> 5;
#pragma unroll
  for (int i = 0; i < 4; ++i) {
    int r = tg * 4 + i;
    tile[r][tx] = in[(size_t)(r0 + r) * C + c0 + tx];
  }
  __syncthreads();
#pragma unroll
  for (int i = 0; i < 4; ++i) {
    int c = tg * 4 + i;
    out[(size_t)(c0 + c) * R + r0 + tx] = f2bf(tile[tx][c]);
  }
}

// --------------- QKV GEMM: 128x256 tile, 8-wave, pipelined ---------------
// C = A[M][K] * Bt[N][K]^T + bias; outputs split to q/k (bf16 [bh][t][d],
// q scaled by log2e/8) and vT (bf16 [bh][d][t]). M=8192 N=3072 K=1024.
// 512 threads = 8 waves (2M x 4N), per-wave C = 64x64 (4x4 16x16 frags,
// acc = 64 VGPR). LDS: dbuf x (A 128x64 + B 256x64) bf16 = 96KB dynamic.
// XOR-swizzled via pre-swizzled global source (linear LDS dest).

__global__ __launch_bounds__(512, 2) void qkv_gemm_kernel(
    const short* __restrict__ A, const short* __restrict__ Bt,
    const float* __restrict__ bias,
    short* __restrict__ oq, short* __restrict__ ok, short* __restrict__ ovt,
    int M, int N, int K) {
  extern __shared__ short lds[];
  const int NT = K >> 6;  // 16 K-tiles
  const int lane = threadIdx.x & 63, wave = threadIdx.x >> 6;
  const int quad = lane >> 4, l16 = lane & 15;
  const int wm2 = wave >> 2, wn4 = wave & 3;

  // bijective XCD swizzle (768 % 8 == 0); n varies fastest within an XCD
  // chunk -> A-panel reuse within an XCD's L2.
  const int nbn = N >> 8;  // 12
  const int swz = (blockIdx.x & 7) * ((int)gridDim.x >> 3) + (blockIdx.x >> 3);
  const int m0 = (swz / nbn) * 128, n0 = (swz % nbn) * 256;

  // staging: per gld, wave w covers 8 rows (w*8 + lane>>3) x 8 16B segs,
  // global seg XOR-pre-swizzled so linear LDS dest yields swizzled layout.
  const int r8 = lane >> 3;
  const int sw8 = ((lane & 7) ^ r8) * 8;
  const short* Ab0 = A + (size_t)(m0 + wave * 8 + r8) * K + sw8;
  const short* Bb0 = Bt + (size_t)(n0 + wave * 8 + r8) * K + sw8;
  short* ldsw = lds + wave * 512;

  // buffer: [A 128x64 | B 256x64] = 24576 shorts (48KB); double-buffered.
  auto stage = [&](int t, int mat, int rA, int rB) {
    const short* g = (mat ? Bb0 : Ab0) + t * 64;
    short* d = ldsw + (t & 1) * 24576 + mat * 8192;
    gld_lds16(g + (size_t)rA * K, d + rA * 64);
    gld_lds16(g + (size_t)rB * K, d + rB * 64);
  };

  // fragment read base addresses (bytes): swizzle term is frag-invariant.
  const int swz0 = ((0 + quad) ^ (l16 & 7)) * 16;  // kh=0
  const int swz1 = ((4 + quad) ^ (l16 & 7)) * 16;  // kh=1
  const int baseA0 = wm2 * 8192 + l16 * 128 + swz0;
  const int baseA1 = wm2 * 8192 + l16 * 128 + swz1;
  const int baseB0 = 16384 + wn4 * 8192 + l16 * 128 + swz0;
  const int baseB1 = 16384 + wn4 * 8192 + l16 * 128 + swz1;

  f32x4 acc[4][4] = {};

  // prologue: stage tile 0 fully (3 chunk-pairs = 6 gld/thread)
  stage(0, 1, 0, 64);
  stage(0, 1, 128, 192);
  stage(0, 0, 0, 64);
  asm volatile("s_waitcnt vmcnt(0)" ::: "memory");
  barx();

#pragma unroll 1
  for (int t = 0; t < NT; ++t) {
    const int vb = (t & 1) * 49152;
    const int aA0 = baseA0 + vb, aA1 = baseA1 + vb;
    const int aB0 = baseB0 + vb, aB1 = baseB1 + vb;
    short8 a0[4], b0[4], a1[4], b1[4];

    // issue kh0 window (8 reads)
    b0[0] = dsr<0>(aB0);     b0[1] = dsr<2048>(aB0);
    b0[2] = dsr<4096>(aB0);  b0[3] = dsr<6144>(aB0);
    a0[0] = dsr<0>(aA0);     a0[1] = dsr<2048>(aA0);
    a0[2] = dsr<4096>(aA0);  a0[3] = dsr<6144>(aA0);
    // stage tile t+1 into the other buffer (vmcnt only; DS retire in-order)
    if (t + 1 < NT) {
      stage(t + 1, 1, 0, 64);
      stage(t + 1, 1, 128, 192);
      stage(t + 1, 0, 0, 64);
    }
    // issue kh1 window (8 more reads; serviced under kh0 MFMAs)
    b1[0] = dsr<0>(aB1);     b1[1] = dsr<2048>(aB1);
    b1[2] = dsr<4096>(aB1);  b1[3] = dsr<6144>(aB1);
    a1[0] = dsr<0>(aA1);     a1[1] = dsr<2048>(aA1);
    a1[2] = dsr<4096>(aA1);  a1[3] = dsr<6144>(aA1);

    WAITLN(8)  // kh0's 8 reads retired (DS in-order); kh1 still in flight
    __builtin_amdgcn_s_setprio(1);
#pragma unroll
    for (int i_ = 0; i_ < 4; ++i_)
#pragma unroll
      for (int n_ = 0; n_ < 4; ++n_)
        acc[i_][n_] = __builtin_amdgcn_mfma_f32_16x16x32_bf16(
            a0[i_], b0[n_], acc[i_][n_], 0, 0, 0);
    __builtin_amdgcn_s_setprio(0);

    WAITLN(0)  // kh1 ready
    __builtin_amdgcn_s_setprio(1);
#pragma unroll
    for (int i_ = 0; i_ < 4; ++i_)
#pragma unroll
      for (int n_ = 0; n_ < 4; ++n_)
        acc[i_][n_] = __builtin_amdgcn_mfma_f32_16x16x32_bf16(
            a1[i_], b1[n_], acc[i_][n_], 0, 0, 0);
    __builtin_amdgcn_s_setprio(0);

    // own DMAs for tile t+1 must land before any wave crosses the barrier
    if (t + 1 < NT)
      asm volatile("s_waitcnt vmcnt(0)" ::: "memory");
    barx();
  }

  // ------------------------------ epilogue (single pass) -----------------
  const int sec = n0 >> 10;                 // 0=q 1=k 2=v
  const int h0 = (n0 & 1023) >> 6;
  const float scale = (sec == 0) ? 0.18033688f : 1.0f;  // log2e/8 into q
  float bv[4];
#pragma unroll
  for (int n_ = 0; n_ < 4; ++n_) bv[n_] = bias[n0 + wn4 * 64 + n_ * 16 + l16];
  const int b_ = m0 >> 11, t0 = m0 & 2047;

  __syncthreads();  // all waves past K-loop; LDS free for repack
  if (sec < 2) {
    // Cs[128][264] bf16 (67.6KB); rows = 128 t, cols = 256 (4 heads x 64 d)
    short* dst = (sec == 0) ? oq : ok;
#pragma unroll
    for (int mt = 0; mt < 4; ++mt)
#pragma unroll
      for (int n_ = 0; n_ < 4; ++n_) {
        const int col = wn4 * 64 + n_ * 16 + l16;
#pragma unroll
        for (int r = 0; r < 4; ++r)
          lds[(wm2 * 64 + mt * 16 + quad * 4 + r) * 264 + col] =
              f2bf((acc[mt][n_][r] + bv[n_]) * scale);
      }
    __syncthreads();
    // wave w: head w&3, row-half w>>2; each iter = 8 t-rows x 64 d = 1KB
    const int hl = wave & 3, rg = wave >> 2;
    const short* sp = &lds[(rg * 64 + r8) * 264 + hl * 64 + (lane & 7) * 8];
    short* gp = dst +
        ((size_t)(b_ * 16 + h0 + hl) * 2048 + t0 + rg * 64 + r8) * 64 +
        (lane & 7) * 8;
#pragma unroll
    for (int i = 0; i < 8; ++i)
      *(short8*)(gp + (size_t)i * 512) = *(const short8*)(sp + i * 8 * 264);
  } else {
    // v: transposed repack; Cs[256 cols][136] bf16 (69.6KB)
#pragma unroll
    for (int mt = 0; mt < 4; ++mt)
#pragma unroll
      for (int n_ = 0; n_ < 4; ++n_) {
        const int col = wn4 * 64 + n_ * 16 + l16;
#pragma unroll
        for (int r = 0; r < 4; ++r)
          lds[col * 136 + wm2 * 64 + mt * 16 + quad * 4 + r] =
              f2bf(acc[mt][n_][r] + bv[n_]);
      }
    __syncthreads();
    // wave w covers cols [w*32,+32): 16 lanes per col, 8 rows each
    const int cw = wave * 32 + (lane >> 4);
#pragma unroll
    for (int i = 0; i < 8; ++i) {
      const int c = cw + i * 4;
      const int bh = b_ * 16 + h0 + (c >> 6), d = c & 63;
      *(short8*)(ovt + ((size_t)bh * 64 + d) * 2048 + t0 + (lane & 15) * 8) =
          *(const short8*)&lds[c * 136 + (lane & 15) * 8];
    }
  }
}

// ------------------------- proj GEMM (unchanged) -------------------------
// C[m][n] = sum_k A[m][k]*B[k][n] + bias[n], A bf16 [M][K], Bt bf16 [N][K].
// BK=64, XOR-swizzled LDS staging. MODE 1: fp32 out [M][N] direct.
template <int MODE>
__global__ __launch_bounds__(256) void gemm_bt_kernel(
    const short* __restrict__ A, const short* __restrict__ Bt,
    const float* __restrict__ bias, float* __restrict__ outf,
    short* __restrict__ oq, short* __restrict__ ok, short* __restrict__ ovt,
    int M, int N, int K) {
  __shared__ short slds[16384];  // As[128][64] + Bs[128][64] = 32KB
  short* As = slds;
  short* Bs = slds + 8192;
  const int m0 = blockIdx.y * 128, n0 = blockIdx.x * 128;
  const int lane = threadIdx.x & 63, wave = threadIdx.x >> 6;
  const int quad = lane >> 4, l16 = lane & 15;
  const int wm = (wave >> 1) * 64, wn = (wave & 1) * 64;

  const int row_off = lane >> 3;                 // 0..7
  const int segsw = ((lane & 7) ^ row_off) * 8;  // XOR-swizzled global seg
  const short* Ag = A + (size_t)(m0 + wave * 32 + row_off) * K + segsw;
  const short* Bg = Bt + (size_t)(n0 + wave * 32 + row_off) * K + segsw;

  f32x4 acc[4][4] = {};

  for (int k0 = 0; k0 < K; k0 += 64) {
#pragma unroll
    for (int g = 0; g < 4; ++g) {
      gld_lds16(Ag + (size_t)(g * 8) * K + k0, &As[(wave * 32 + g * 8) * 64]);
      gld_lds16(Bg + (size_t)(g * 8) * K + k0, &Bs[(wave * 32 + g * 8) * 64]);
    }
    __syncthreads();
#pragma unroll
    for (int kh = 0; kh < 2; ++kh) {
      short8 a[4], b[4];
#pragma unroll
      for (int t = 0; t < 4; ++t) {
        const int R = wm + t * 16 + l16;
        a[t] = *(const short8*)&As[R * 64 + (((kh * 4 + quad) ^ (R & 7)) * 8)];
      }
#pragma unroll
      for (int t = 0; t < 4; ++t) {
        const int R = wn + t * 16 + l16;
        b[t] = *(const short8*)&Bs[R * 64 + (((kh * 4 + quad) ^ (R & 7)) * 8)];
      }
#pragma unroll
      for (int mt = 0; mt < 4; ++mt)
#pragma unroll
        for (int nt = 0; nt < 4; ++nt)
          acc[mt][nt] = __builtin_amdgcn_mfma_f32_16x16x32_bf16(
              a[mt], b[nt], acc[mt][nt], 0, 0, 0);
    }
    __syncthreads();
  }

  float bv[4];
#pragma unroll
  for (int nt = 0; nt < 4; ++nt) bv[nt] = bias[n0 + wn + nt * 16 + l16];

  if (MODE == 1) {
#pragma unroll
    for (int mt = 0; mt < 4; ++mt)
#pragma unroll
      for (int nt = 0; nt < 4; ++nt) {
        const int n = n0 + wn + nt * 16 + l16;
#pragma unroll
        for (int r = 0; r < 4; ++r) {
          const int m = m0 + wm + mt * 16 + quad * 4 + r;
          outf[(size_t)m * N + n] = acc[mt][nt][r] + bv[nt];
        }
      }
  }
}

// --------------------------- flash attention -----------------------------
// (round-5 version, unchanged)
__global__ __launch_bounds__(256, 6) void attn_kernel(
    const short* __restrict__ q, const short* __restrict__ k,
    const short* __restrict__ vt, short* __restrict__ y) {
  __shared__ short Ks[64 * 64];
  __shared__ short Vs[64 * 64];
  __shared__ short Ps[4][16 * 72];
  const int lane = threadIdx.x & 63, wave = threadIdx.x >> 6;
  const int quad = lane >> 4, l16 = lane & 15;
  const int g = blockIdx.x;
  const int bh = g & 63;
  const int j = 31 - (g >> 6);  // big blocks dispatched first
  const int b_ = bh >> 4, h = bh & 15;
  const int q0 = j * 64 + wave * 16;

  const short* qbh = q + (size_t)bh * 2048 * 64;
  const short* kbh = k + (size_t)bh * 2048 * 64;
  const short* vbh = vt + (size_t)bh * 64 * 2048;
  short* Pw = Ps[wave];

  const short8 qf0 = *(const short8*)&qbh[(q0 + l16) * 64 + quad * 8];
  const short8 qf1 = *(const short8*)&qbh[(q0 + l16) * 64 + 32 + quad * 8];

  short8 ones;
#pragma unroll
  for (int i = 0; i < 8; ++i) ones[i] = (short)0x3F80;  // bf16 1.0

  f32x4 O[4] = {};
  f32x4 lacc = {};

  const int srow = lane >> 3;
  const int scol = ((lane & 7) ^ srow) * 8;
  const int r0s = wave * 16;

#pragma unroll 1
  for (int c = 0; c <= j; ++c) {
    const int kt0 = c * 64;
    gld_lds16(kbh + (size_t)(kt0 + r0s + srow) * 64 + scol, &Ks[r0s * 64]);
    gld_lds16(kbh + (size_t)(kt0 + r0s + 8 + srow) * 64 + scol, &Ks[(r0s + 8) * 64]);
    gld_lds16(vbh + (size_t)(r0s + srow) * 2048 + kt0 + scol, &Vs[r0s * 64]);
    gld_lds16(vbh + (size_t)(r0s + 8 + srow) * 2048 + kt0 + scol, &Vs[(r0s + 8) * 64]);
    __syncthreads();

    const int sw = l16 & 7;
    f32x4 sc4[4];
#pragma unroll
    for (int cf = 0; cf < 4; ++cf) {
      const int row = cf * 16 + l16;
      const short8 kfa = *(const short8*)&Ks[row * 64 + ((quad ^ sw) * 8)];
      const short8 kfb = *(const short8*)&Ks[row * 64 + (((quad + 4) ^ sw) * 8)];
      f32x4 z = {};
      z = __builtin_amdgcn_mfma_f32_16x16x32_bf16(qf0, kfa, z, 0, 0, 0);
      z = __builtin_amdgcn_mfma_f32_16x16x32_bf16(qf1, kfb, z, 0, 0, 0);
      sc4[cf] = z;
    }

    if (c == j) {
#pragma unroll
      for (int cf = 0; cf < 4; ++cf) {
        const int col = kt0 + cf * 16 + l16;
#pragma unroll
        for (int r = 0; r < 4; ++r) {
          const int rowg = q0 + quad * 4 + r;
          float e = exp2_fast(sc4[cf][r]);
          e = (col > rowg) ? 0.f : e;
          Pw[(quad * 4 + r) * 72 + cf * 16 + l16] = f2bf(e);
        }
      }
    } else {
#pragma unroll
      for (int cf = 0; cf < 4; ++cf)
#pragma unroll
        for (int r = 0; r < 4; ++r)
          Pw[(quad * 4 + r) * 72 + cf * 16 + l16] = f2bf(exp2_fast(sc4[cf][r]));
    }
    asm volatile("s_waitcnt lgkmcnt(0)" ::: "memory");
    const short8 pf0 = *(const short8*)&Pw[l16 * 72 + quad * 8];
    const short8 pf1 = *(const short8*)&Pw[l16 * 72 + 32 + quad * 8];

    lacc = __builtin_amdgcn_mfma_f32_16x16x32_bf16(pf0, ones, lacc, 0, 0, 0);
    lacc = __builtin_amdgcn_mfma_f32_16x16x32_bf16(pf1, ones, lacc, 0, 0, 0);

#pragma unroll
    for (int dt = 0; dt < 4; ++dt) {
      const int d = dt * 16 + l16;
      const short8 vf0 = *(const short8*)&Vs[d * 64 + ((quad ^ sw) * 8)];
      const short8 vf1 = *(const short8*)&Vs[d * 64 + (((quad + 4) ^ sw) * 8)];
      O[dt] = __builtin_amdgcn_mfma_f32_16x16x32_bf16(pf0, vf0, O[dt], 0, 0, 0);
      O[dt] = __builtin_amdgcn_mfma_f32_16x16x32_bf16(pf1, vf1, O[dt], 0, 0, 0);
    }
    __syncthreads();
  }

  float inv[4];
#pragma unroll
  for (int r = 0; r < 4; ++r) inv[r] = 1.0f / lacc[r];
#pragma unroll
  for (int dt = 0; dt < 4; ++dt) {
    const int d = dt * 16 + l16;
#pragma unroll
    for (int r = 0; r < 4; ++r) {
      const int t_ = q0 + quad * 4 + r;
      y[((size_t)b_ * 2048 + t_) * 1024 + h * 64 + d] = f2bf(O[dt][r] * inv[r]);
    }
  }
}

// -------------------------------------------------------------------------
extern "C" void kernel_launch(void* const* d_in, const int* in_sizes, int n_in,
                              void* d_out, int out_size, void* d_ws, size_t ws_size,
                              hipStream_t stream) {
  const float* x      = (const float*)d_in[0];
  const float* w_attn = (const float*)d_in[1];
  const float* b_attn = (const float*)d_in[2];
  const float* w_proj = (const float*)d_in[3];
  const float* b_proj = (const float*)d_in[4];
  float* out = (float*)d_out;

  short* xb  = (short*)d_ws;                    // [8192][1024]
  short* wTa = xb + (size_t)8192 * 1024;        // [3072][1024]
  short* wTp = wTa + (size_t)3072 * 1024;       // [1024][1024]
  short* qb  = wTp + (size_t)1024 * 1024;       // [64][2048][64]
  short* kb  = qb + (size_t)64 * 2048 * 64;     // [64][2048][64]
  short* vtb = kb + (size_t)64 * 2048 * 64;     // [64][64][2048]
  short* yb  = vtb + (size_t)64 * 2048 * 64;    // [8192][1024]

  static int lds_attr_done = 0;
  if (!lds_attr_done) {
    (void)hipFuncSetAttribute(reinterpret_cast<const void*>(qkv_gemm_kernel),
                              hipFuncAttributeMaxDynamicSharedMemorySize,
                              98304);
    lds_attr_done = 1;
  }

  cast_bf16_kernel<<<8192, 256, 0, stream>>>(x, xb, 8192 * 1024 / 4);
  transpose_cast_kernel<<<dim3(96, 32), 256, 0, stream>>>(w_attn, wTa, 1024, 3072);
  transpose_cast_kernel<<<dim3(32, 32), 256, 0, stream>>>(w_proj, wTp, 1024, 1024);

  qkv_gemm_kernel<<<768, 512, 98304, stream>>>(
      xb, wTa, b_attn, qb, kb, vtb, 8192, 3072, 1024);

  attn_kernel<<<2048, 256, 0, stream>>>(qb, kb, vtb, yb);

  gemm_bt_kernel<1><<<dim3(8, 64), 256, 0, stream>>>(
      yb, wTp, b_proj, out, nullptr, nullptr, nullptr, 8192, 1024, 1024);
}